// Round 11
// baseline (37.200 us; speedup 1.0000x reference)
//
#include <hip/hip_runtime.h>

// Inception Temporal Layer — 3 causal VALID conv1d + leaky_relu(0.01).
// x[8192][512][4] f32; w1[16][4][6]; w2[16][16][4]; w3[16][16][13]; out[8192][3][48][16].
// Cone: o3[t<48] <- even o2[0..142] <- o1[0..148] <- x[0..449].
//
// Round 11 = round 8 (MFMA, frag-ready weights in d_ws, 1 wave/row, 49 MFMA)
// with stage-1's uncoalesced x loads fixed:
//   x staged COALESCED into LDS as bf16 [t][4] (8B rows): 8 x float4/wave
//   (1KB/instr) + pack + ds_write_b64; A-frags then come from 2x ds_read_b64
//   (k-order kk*4+ch == [t][4] layout). Kills ~20 scattered global loads
//   (~1000 L1 transactions/wave) and ~280 pack-VALU per wave.
// Same accumulation order/rounding as round 8 -> absmax 0.03125 exactly.
//
// Frag maps (m89-verified): A row = l&15, k = 8*(l>>4)+e; B col = l&15, same k;
// D col = l&15, row = 4*(l>>4)+r.
// K-orders: stage1 k = kk*4+ch (K=24 pad 32); stages 2/3 k = kk*16+ci
// (K=64; K=208 pad 224) so A-frag = 8 consecutive ci = one ds_read_b128.

typedef __attribute__((ext_vector_type(8))) short bf16x8;
typedef __attribute__((ext_vector_type(4))) float f32x4;
typedef __attribute__((ext_vector_type(4))) unsigned int u32x4;
typedef __attribute__((ext_vector_type(2))) unsigned int u32x2;

union FragU { u32x4 u; bf16x8 b; };

__device__ __forceinline__ unsigned short f2bf(float f) {   // RTN-even
    unsigned int u = __builtin_bit_cast(unsigned int, f);
    u += 0x7FFFu + ((u >> 16) & 1u);
    return (unsigned short)(u >> 16);
}
__device__ __forceinline__ unsigned int pack2bf(float lo, float hi) {
    return (unsigned int)f2bf(lo) | ((unsigned int)f2bf(hi) << 16);
}

// d_ws u32 layout (frag-ready B, bf16 pairs; pair kp holds k=2kp lo, 2kp+1 hi):
//   [0..255]     B1[kp*16+co], k = kk*4+ch  (K=24, kp>=12 -> 0)
//   [256..767]   B2[kp*16+co], k = kk*16+ci (K=64)
//   [768..2559]  B3[kp*16+co], k = kk*16+ci (K=208, kk=13 -> 0)
//   f32: [2560..2575] b1, [2576..2591] b2, [2592..2607] b3
__global__ void wtrans_kernel(const float* __restrict__ w1, const float* __restrict__ b1,
                              const float* __restrict__ w2, const float* __restrict__ b2,
                              const float* __restrict__ w3, const float* __restrict__ b3,
                              unsigned int* __restrict__ ws) {
    const int tid = threadIdx.x;                    // 256 threads
    if (tid < 256) {                                // B1: k = kk*4 + ch
        int kp = tid >> 4, co = tid & 15;
        int k0 = 2 * kp, k1 = k0 + 1;
        float v0 = (k0 < 24) ? w1[co * 24 + (k0 & 3) * 6 + (k0 >> 2)] : 0.f;
        float v1 = (k1 < 24) ? w1[co * 24 + (k1 & 3) * 6 + (k1 >> 2)] : 0.f;
        ws[tid] = pack2bf(v0, v1);
    }
    for (int p = tid; p < 512; p += 256) {          // B2: k = kk*16 + ci
        int kp = p >> 4, co = p & 15;
        int k0 = 2 * kp, ci0 = k0 & 15, kk = k0 >> 4;
        ws[256 + p] = pack2bf(w2[co * 64 + ci0 * 4 + kk],
                              w2[co * 64 + (ci0 + 1) * 4 + kk]);
    }
    for (int p = tid; p < 1792; p += 256) {         // B3: k = kk*16 + ci
        int kp = p >> 4, co = p & 15;
        int k0 = 2 * kp, ci0 = k0 & 15, kk = k0 >> 4;
        float v0 = (kk < 13) ? w3[co * 208 + ci0 * 13 + kk] : 0.f;
        float v1 = (kk < 13) ? w3[co * 208 + (ci0 + 1) * 13 + kk] : 0.f;
        ws[768 + p] = pack2bf(v0, v1);
    }
    float* wf = (float*)ws;
    if (tid < 16) { wf[2560 + tid] = b1[tid]; wf[2576 + tid] = b2[tid]; wf[2592 + tid] = b3[tid]; }
}

__global__ __launch_bounds__(64, 4) void itl_kernel(
    const float* __restrict__ x,
    const unsigned int* __restrict__ wt,
    float* __restrict__ out)
{
    __shared__ __align__(16) unsigned short o1b[160 * 24];  // bf16 o1[t][ci], 48B rows
    __shared__ __align__(16) unsigned short o2e[76 * 24];   // bf16 even-o2 [slot][ci]
    __shared__ __align__(16) unsigned short xb[488 * 4];    // bf16 x[t][ch], 8B rows

    const int lane = threadIdx.x;        // 0..63, one wave per row
    const int n    = blockIdx.x;
    const int co   = lane & 15;          // A-row / B-col / D-col index
    const int g    = lane >> 4;          // 0..3
    const int gh   = g >> 1;             // (l>>5)
    const int cib  = 8 * (g & 1);        // ci base of this lane's A elements

    const float4* x4 = reinterpret_cast<const float4*>(x) + (size_t)n * 512;
    const float* wf  = (const float*)wt;
    float* outn = out + (size_t)n * 2304;

    // zero the o2e pad rows 72..75 (read under zero-B k-padding in stage 3)
    if (lane < 48) reinterpret_cast<unsigned int*>(o2e)[72 * 12 + lane] = 0u;

    // ---------------- stage x: coalesced global -> bf16 LDS [t][4] -------------
    {
        unsigned int* xw = reinterpret_cast<unsigned int*>(xb);
        #pragma unroll
        for (int i = 0; i < 7; ++i) {
            const int row = 64 * i + lane;           // < 448+63 < 488
            float4 v = x4[row];
            xw[row * 2]     = pack2bf(v.x, v.y);
            xw[row * 2 + 1] = pack2bf(v.z, v.w);
        }
        if (lane < 40) {
            const int row = 448 + lane;              // 448..487 < 512
            float4 v = x4[row];
            xw[row * 2]     = pack2bf(v.x, v.y);
            xw[row * 2 + 1] = pack2bf(v.z, v.w);
        }
    }

    // ---------------- stage 1: 10 tiles, K=24 pad 32 ---------------------------
    {
        FragU b1f;
        #pragma unroll
        for (int p = 0; p < 4; ++p) b1f.u[p] = wt[(4 * g + p) * 16 + co];
        const float bias1 = wf[2560 + co];
        #pragma unroll
        for (int ti = 0; ti < 10; ++ti) {
            const int j0 = 16 * ti;
            const int t  = j0 + co;
            const int r0 = 3 * t + 2 * g;            // A rows r0, r0+1; max 484 < 488
            FragU a;
            u32x2 alo = *reinterpret_cast<const u32x2*>(&xb[r0 * 4]);
            u32x2 ahi = *reinterpret_cast<const u32x2*>(&xb[(r0 + 1) * 4]);
            a.u[0] = alo[0]; a.u[1] = alo[1];
            a.u[2] = ahi[0]; a.u[3] = ahi[1];        // g=3: real data x zero-B = 0
            f32x4 acc = {bias1, bias1, bias1, bias1};
            acc = __builtin_amdgcn_mfma_f32_16x16x32_bf16(a.b, b1f.b, acc, 0, 0, 0);
            const int tD = j0 + 4 * g;               // D row = 4*(l>>4)+r
            #pragma unroll
            for (int r = 0; r < 4; ++r) {
                float v = acc[r]; v = fmaxf(v, 0.01f * v);
                o1b[(tD + r) * 24 + co] = f2bf(v);           // rows <= 159 < 160
                if (ti < 3) outn[(tD + r) * 16 + co] = v;    // scale 0, t<48
            }
        }
    }

    // ---------------- stage 2: 9 tiles x 2 k-steps, K=64 -----------------------
    {
        FragU b2f[2];
        #pragma unroll
        for (int kb = 0; kb < 2; ++kb)
            #pragma unroll
            for (int p = 0; p < 4; ++p)
                b2f[kb].u[p] = wt[256 + (16 * kb + 4 * g + p) * 16 + co];
        const float bias2 = wf[2576 + co];
        #pragma unroll
        for (int ti = 0; ti < 9; ++ti) {
            const int j0 = 16 * ti;
            f32x4 acc = {bias2, bias2, bias2, bias2};
            #pragma unroll
            for (int kb = 0; kb < 2; ++kb) {
                const int row = j0 + co + 2 * (2 * kb + gh);    // <= 149
                FragU a; a.u = *(const u32x4*)&o1b[row * 24 + cib];
                acc = __builtin_amdgcn_mfma_f32_16x16x32_bf16(a.b, b2f[kb].b, acc, 0, 0, 0);
            }
            const int jD = j0 + 4 * g;
            #pragma unroll
            for (int r = 0; r < 4; ++r) {
                float v = acc[r]; v = fmaxf(v, 0.01f * v);
                if ((r & 1) == 0) o2e[((jD + r) >> 1) * 24 + co] = f2bf(v);  // even j
                if (ti < 3) outn[768 + (jD + r) * 16 + co] = v;  // scale 1, j<48
            }
        }
    }

    // ---------------- stage 3: 3 tiles x 7 k-steps, K=208 pad 224 --------------
    {
        FragU b3f[7];
        #pragma unroll
        for (int kb = 0; kb < 7; ++kb)
            #pragma unroll
            for (int p = 0; p < 4; ++p)
                b3f[kb].u[p] = wt[768 + (16 * kb + 4 * g + p) * 16 + co];
        const float bias3 = wf[2592 + co];
        #pragma unroll
        for (int ti = 0; ti < 3; ++ti) {
            const int t0 = 16 * ti;
            f32x4 acc = {bias3, bias3, bias3, bias3};
            #pragma unroll
            for (int kb = 0; kb < 7; ++kb) {
                const int row = t0 + co + 2 * (2 * kb + gh);    // <= 73 < 76
                FragU a; a.u = *(const u32x4*)&o2e[row * 24 + cib];
                acc = __builtin_amdgcn_mfma_f32_16x16x32_bf16(a.b, b3f[kb].b, acc, 0, 0, 0);
            }
            const int tD = t0 + 4 * g;
            #pragma unroll
            for (int r = 0; r < 4; ++r) {
                float v = acc[r]; v = fmaxf(v, 0.01f * v);
                outn[1536 + (tD + r) * 16 + co] = v;            // scale 2
            }
        }
    }
}

extern "C" void kernel_launch(void* const* d_in, const int* in_sizes, int n_in,
                              void* d_out, int out_size, void* d_ws, size_t ws_size,
                              hipStream_t stream) {
    const float* x  = (const float*)d_in[0];
    const float* w1 = (const float*)d_in[1];
    const float* b1 = (const float*)d_in[2];
    const float* w2 = (const float*)d_in[3];
    const float* b2 = (const float*)d_in[4];
    const float* w3 = (const float*)d_in[5];
    const float* b3 = (const float*)d_in[6];
    float* out = (float*)d_out;
    unsigned int* ws = (unsigned int*)d_ws;           // 2608 u32 = 10.4 KB

    wtrans_kernel<<<1, 256, 0, stream>>>(w1, b1, w2, b2, w3, b3, ws);
    itl_kernel<<<8192, 64, 0, stream>>>(x, ws, out);  // 1 row per wave
}

// Round 12
// 34.905 us; speedup vs baseline: 1.0657x; 1.0657x over previous
//
#include <hip/hip_runtime.h>

// Inception Temporal Layer — 3 causal VALID conv1d + leaky_relu(0.01).
// x[8192][512][4] f32; w1[16][4][6]; w2[16][16][4]; w3[16][16][13]; out[8192][3][48][16].
// Cone: o3[t<48] <- even o2[0..142] <- o1[0..148] <- x[0..449].
//
// Round 12 = round 8 (MFMA, frag-ready weights in d_ws, 1 wave/row, 49 MFMA)
// + MAX memory-level parallelism: ALL global loads (20x dwordx4 of x, 40
// weight-frag dwords, 3 biases) issued at kernel entry into registers.
// r8/r10/r11 all sat at 34-37us with VGPR~52: the compiler kept only ~2
// loads in flight, serializing ~10 L2/L3-latency waits per wave. This round
// spends VGPRs (~140, launch_bounds(64,3)) to keep ~60 loads outstanding.
// g==3 lanes load real (in-bounds) data instead of zeros: their B-columns
// are 0 so contribution is +0.0 — math identical to r8, absmax 0.03125.
//
// Frag maps (m89-verified): A row = l&15, k = 8*(l>>4)+e; B col = l&15, same k;
// D col = l&15, row = 4*(l>>4)+r.
// K-orders: stage1 k = kk*4+ch (K=24 pad 32); stages 2/3 k = kk*16+ci
// (K=64; K=208 pad 224) so A-frag = 8 consecutive ci = one ds_read_b128.

typedef __attribute__((ext_vector_type(8))) short bf16x8;
typedef __attribute__((ext_vector_type(4))) float f32x4;
typedef __attribute__((ext_vector_type(4))) unsigned int u32x4;

union FragU { u32x4 u; bf16x8 b; };

__device__ __forceinline__ unsigned short f2bf(float f) {   // RTN-even
    unsigned int u = __builtin_bit_cast(unsigned int, f);
    u += 0x7FFFu + ((u >> 16) & 1u);
    return (unsigned short)(u >> 16);
}
__device__ __forceinline__ unsigned int pack2bf(float lo, float hi) {
    return (unsigned int)f2bf(lo) | ((unsigned int)f2bf(hi) << 16);
}

// d_ws u32 layout (frag-ready B, bf16 pairs; pair kp holds k=2kp lo, 2kp+1 hi):
//   [0..255]     B1[kp*16+co], k = kk*4+ch  (K=24, kp>=12 -> 0)
//   [256..767]   B2[kp*16+co], k = kk*16+ci (K=64)
//   [768..2559]  B3[kp*16+co], k = kk*16+ci (K=208, kk=13 -> 0)
//   f32: [2560..2575] b1, [2576..2591] b2, [2592..2607] b3
__global__ void wtrans_kernel(const float* __restrict__ w1, const float* __restrict__ b1,
                              const float* __restrict__ w2, const float* __restrict__ b2,
                              const float* __restrict__ w3, const float* __restrict__ b3,
                              unsigned int* __restrict__ ws) {
    const int tid = threadIdx.x;                    // 256 threads
    if (tid < 256) {                                // B1: k = kk*4 + ch
        int kp = tid >> 4, co = tid & 15;
        int k0 = 2 * kp, k1 = k0 + 1;
        float v0 = (k0 < 24) ? w1[co * 24 + (k0 & 3) * 6 + (k0 >> 2)] : 0.f;
        float v1 = (k1 < 24) ? w1[co * 24 + (k1 & 3) * 6 + (k1 >> 2)] : 0.f;
        ws[tid] = pack2bf(v0, v1);
    }
    for (int p = tid; p < 512; p += 256) {          // B2: k = kk*16 + ci
        int kp = p >> 4, co = p & 15;
        int k0 = 2 * kp, ci0 = k0 & 15, kk = k0 >> 4;
        ws[256 + p] = pack2bf(w2[co * 64 + ci0 * 4 + kk],
                              w2[co * 64 + (ci0 + 1) * 4 + kk]);
    }
    for (int p = tid; p < 1792; p += 256) {         // B3: k = kk*16 + ci
        int kp = p >> 4, co = p & 15;
        int k0 = 2 * kp, ci0 = k0 & 15, kk = k0 >> 4;
        float v0 = (kk < 13) ? w3[co * 208 + ci0 * 13 + kk] : 0.f;
        float v1 = (kk < 13) ? w3[co * 208 + (ci0 + 1) * 13 + kk] : 0.f;
        ws[768 + p] = pack2bf(v0, v1);
    }
    float* wf = (float*)ws;
    if (tid < 16) { wf[2560 + tid] = b1[tid]; wf[2576 + tid] = b2[tid]; wf[2592 + tid] = b3[tid]; }
}

__global__ __launch_bounds__(64, 3) void itl_kernel(
    const float* __restrict__ x,
    const unsigned int* __restrict__ wt,
    float* __restrict__ out)
{
    __shared__ __align__(16) unsigned short o1b[160 * 24];  // bf16 o1[t][ci], 48B rows
    __shared__ __align__(16) unsigned short o2e[76 * 24];   // bf16 even-o2 [slot][ci]

    const int lane = threadIdx.x;        // 0..63, one wave per row
    const int n    = blockIdx.x;
    const int co   = lane & 15;          // A-row / B-col / D-col index
    const int g    = lane >> 4;          // 0..3
    const int gh   = g >> 1;             // (l>>5)
    const int cib  = 8 * (g & 1);        // ci base of this lane's A elements

    const float4* x4 = reinterpret_cast<const float4*>(x) + (size_t)n * 512;
    const float* wf  = (const float*)wt;
    float* outn = out + (size_t)n * 2304;

    // ======== issue ALL global loads up front (max outstanding VMEM) ========
    float4 xa[10], xb[10];               // stage-1 x windows, all 10 tiles
    #pragma unroll
    for (int ti = 0; ti < 10; ++ti) {
        const int r0 = 3 * (16 * ti + co) + 2 * g;   // <= 483; +1 = 484 < 512
        xa[ti] = x4[r0];
        xb[ti] = x4[r0 + 1];
    }
    FragU b1f;
    #pragma unroll
    for (int p = 0; p < 4; ++p) b1f.u[p] = wt[(4 * g + p) * 16 + co];
    FragU b2f[2];
    #pragma unroll
    for (int kb = 0; kb < 2; ++kb)
        #pragma unroll
        for (int p = 0; p < 4; ++p)
            b2f[kb].u[p] = wt[256 + (16 * kb + 4 * g + p) * 16 + co];
    FragU b3f[7];
    #pragma unroll
    for (int kb = 0; kb < 7; ++kb)
        #pragma unroll
        for (int p = 0; p < 4; ++p)
            b3f[kb].u[p] = wt[768 + (16 * kb + 4 * g + p) * 16 + co];
    const float bias1 = wf[2560 + co];
    const float bias2 = wf[2576 + co];
    const float bias3 = wf[2592 + co];

    // zero the o2e pad rows 72..75 (read under zero-B k-padding in stage 3)
    if (lane < 48) reinterpret_cast<unsigned int*>(o2e)[72 * 12 + lane] = 0u;

    // ---------------- stage 1: 10 tiles, K=24 pad 32 ---------------------------
    #pragma unroll
    for (int ti = 0; ti < 10; ++ti) {
        const int j0 = 16 * ti;
        FragU a;
        a.u[0] = pack2bf(xa[ti].x, xa[ti].y);
        a.u[1] = pack2bf(xa[ti].z, xa[ti].w);
        a.u[2] = pack2bf(xb[ti].x, xb[ti].y);
        a.u[3] = pack2bf(xb[ti].z, xb[ti].w);   // g=3: real data x zero-B = +0
        f32x4 acc = {bias1, bias1, bias1, bias1};
        acc = __builtin_amdgcn_mfma_f32_16x16x32_bf16(a.b, b1f.b, acc, 0, 0, 0);
        const int tD = j0 + 4 * g;               // D row = 4*(l>>4)+r
        #pragma unroll
        for (int r = 0; r < 4; ++r) {
            float v = acc[r]; v = fmaxf(v, 0.01f * v);
            o1b[(tD + r) * 24 + co] = f2bf(v);           // rows <= 159 < 160
            if (ti < 3) outn[(tD + r) * 16 + co] = v;    // scale 0, t<48
        }
    }

    // ---------------- stage 2: 9 tiles x 2 k-steps, K=64 -----------------------
    {
        #pragma unroll
        for (int ti = 0; ti < 9; ++ti) {
            const int j0 = 16 * ti;
            f32x4 acc = {bias2, bias2, bias2, bias2};
            #pragma unroll
            for (int kb = 0; kb < 2; ++kb) {
                const int row = j0 + co + 2 * (2 * kb + gh);    // <= 149
                FragU a; a.u = *(const u32x4*)&o1b[row * 24 + cib];
                acc = __builtin_amdgcn_mfma_f32_16x16x32_bf16(a.b, b2f[kb].b, acc, 0, 0, 0);
            }
            const int jD = j0 + 4 * g;
            #pragma unroll
            for (int r = 0; r < 4; ++r) {
                float v = acc[r]; v = fmaxf(v, 0.01f * v);
                if ((r & 1) == 0) o2e[((jD + r) >> 1) * 24 + co] = f2bf(v);  // even j
                if (ti < 3) outn[768 + (jD + r) * 16 + co] = v;  // scale 1, j<48
            }
        }
    }

    // ---------------- stage 3: 3 tiles x 7 k-steps, K=208 pad 224 --------------
    {
        #pragma unroll
        for (int ti = 0; ti < 3; ++ti) {
            const int t0 = 16 * ti;
            f32x4 acc = {bias3, bias3, bias3, bias3};
            #pragma unroll
            for (int kb = 0; kb < 7; ++kb) {
                const int row = t0 + co + 2 * (2 * kb + gh);    // <= 73 < 76
                FragU a; a.u = *(const u32x4*)&o2e[row * 24 + cib];
                acc = __builtin_amdgcn_mfma_f32_16x16x32_bf16(a.b, b3f[kb].b, acc, 0, 0, 0);
            }
            const int tD = t0 + 4 * g;
            #pragma unroll
            for (int r = 0; r < 4; ++r) {
                float v = acc[r]; v = fmaxf(v, 0.01f * v);
                outn[1536 + (tD + r) * 16 + co] = v;            // scale 2
            }
        }
    }
}

extern "C" void kernel_launch(void* const* d_in, const int* in_sizes, int n_in,
                              void* d_out, int out_size, void* d_ws, size_t ws_size,
                              hipStream_t stream) {
    const float* x  = (const float*)d_in[0];
    const float* w1 = (const float*)d_in[1];
    const float* b1 = (const float*)d_in[2];
    const float* w2 = (const float*)d_in[3];
    const float* b2 = (const float*)d_in[4];
    const float* w3 = (const float*)d_in[5];
    const float* b3 = (const float*)d_in[6];
    float* out = (float*)d_out;
    unsigned int* ws = (unsigned int*)d_ws;           // 2608 u32 = 10.4 KB

    wtrans_kernel<<<1, 256, 0, stream>>>(w1, b1, w2, b2, w3, b3, ws);
    itl_kernel<<<8192, 64, 0, stream>>>(x, ws, out);  // 1 row per wave
}